// Round 5
// baseline (1187.875 us; speedup 1.0000x reference)
//
#include <hip/hip_runtime.h>

// B=128, T=48, I=128, H=512. Sequential 48-step attention+GRU scan.
// R10: XCD-local exchange (sc0 / L2-latency) with runtime co-residency probe.
//  - Groups are fully partitioned (rows, zg, hgh, flags): exchange is only
//    ever group-internal. If a group's 16 blocks share an XCD (round-robin
//    dispatch => always, in practice), all exchange ops use sc0-only
//    (L1-bypass, serviced by the shared per-XCD L2, ~3x lower latency than
//    the agent-scope MALL bypass).
//  - Placement is NEVER assumed: a 2-round handshake probe THROUGH the sc0
//    path decides per group; on any failure the group uses the R9-proven
//    agent-scope path. Probe is bounded; votes are agent-scope (reliable);
//    all members compute the same verdict from the same vote data.
//  - Fast path: asm sc0 loads/stores; explicit vmcnt(0) drains before flag
//    stores (asm stores are untracked by the compiler's barrier drain);
//    sched_barrier(0) after split waitcnts (guide rule #18).
//  - Everything else identical to R9.

typedef _Float16 half8 __attribute__((ext_vector_type(8)));
typedef _Float16 h2v  __attribute__((ext_vector_type(2)));
typedef float    f32x4 __attribute__((ext_vector_type(4)));
typedef unsigned int u32x3 __attribute__((ext_vector_type(3)));

// ---------------- ws layout (bytes) ----------------
#define OFF_BAR   0u          // flags: zflag[128]*128B @0 (+16..18 probe/votes),
                              //        hflag[128]*128B @16K
#define OFF_BZ    32768u      // 2048 f32 : [b1 ; b_hh]
#define OFF_BC    40960u      // 1536 f32 : W_ih@b4 + b_ih
#define OFF_WZ    65536u      // 2048*512 f16 : [W1 ; W_hh] row-major
#define OFF_WCT   2162688u    // 131*1536 f16 : (W_ih@W4)^T, k-major
#define OFF_W2H   3178496u    // 128*48*512 f16 : dx@W2^T + b2
#define OFF_HGH   9732096u    // 128*512 f16 : h (cross-block exchange)
#define OFF_ZG    9863168u    // 128*2048 f32 : z = [w1 | gh]
#define OFF_DW    10911744u   // 6144*256*3 u32 : dx@Wc^T packed 12B/(t,pair)

__device__ __forceinline__ float fexp2(float x) { return __builtin_amdgcn_exp2f(x); }
__device__ __forceinline__ float frcp(float x)  { return __builtin_amdgcn_rcpf(x); }
__device__ __forceinline__ float fast_tanh(float x) {
  x = fminf(fmaxf(x, -15.f), 15.f);
  float e = fexp2(x * 2.8853900817779268f);   // exp(2x)
  return (e - 1.f) * frcp(e + 1.f);
}
__device__ __forceinline__ float fast_sigmoid(float x) {
  x = fminf(fmaxf(x, -30.f), 30.f);
  float e = fexp2(x * 1.4426950408889634f);   // exp(x)
  return e * frcp(e + 1.f);
}

// ---- agent-scope (MALL, sc0 sc1) ops: the proven slow/fallback path ----
__device__ __forceinline__ void st_f32(float* p, float v) {
  __hip_atomic_store(p, v, __ATOMIC_RELAXED, __HIP_MEMORY_SCOPE_AGENT);
}
__device__ __forceinline__ unsigned long long ld_u64(const void* p) {
  return __hip_atomic_load((const unsigned long long*)p, __ATOMIC_RELAXED,
                           __HIP_MEMORY_SCOPE_AGENT);
}
__device__ __forceinline__ void st_u32(unsigned int* p, unsigned int v) {
  __hip_atomic_store(p, v, __ATOMIC_RELAXED, __HIP_MEMORY_SCOPE_AGENT);
}
union U2 { unsigned long long u; float f[2]; };
union H4 { unsigned long long u; _Float16 h[4]; };
union HU { unsigned int u; h2v h; };

// ---- sc0-only (XCD-L2) ops: fast path ----
__device__ __forceinline__ unsigned int ld_flag_sc0(const unsigned int* p) {
  unsigned int v;
  asm volatile("global_load_dword %0, %1, off sc0\n\t"
               "s_waitcnt vmcnt(0)"
               : "=v"(v) : "v"(p) : "memory");
  return v;
}
__device__ __forceinline__ void st_u32_sc0(unsigned int* p, unsigned int v) {
  asm volatile("global_store_dword %0, %1, off sc0" :: "v"(p), "v"(v) : "memory");
}
__device__ __forceinline__ void st_f32_sc0(float* p, float v) {
  asm volatile("global_store_dword %0, %1, off sc0" :: "v"(p), "v"(v) : "memory");
}
__device__ __forceinline__ void drain_vm() {
  asm volatile("s_waitcnt vmcnt(0)" ::: "memory");
  __builtin_amdgcn_sched_barrier(0);
}

// Wait until *fp >= target on all active lanes (agent scope, slow path).
__device__ __forceinline__ void poll_ge(unsigned int* fp, bool active,
                                        unsigned int target) {
  for (;;) {
    unsigned int v = active
      ? __hip_atomic_load(fp, __ATOMIC_RELAXED, __HIP_MEMORY_SCOPE_AGENT)
      : target;
    if (__ballot(v < target) == 0) break;
    __builtin_amdgcn_s_sleep(1);
  }
  __asm__ __volatile__("" ::: "memory");
}
// All-lane poll, sc0 (fast path). fp must be valid on every lane.
__device__ __forceinline__ void poll_ge_sc0(const unsigned int* fp,
                                            unsigned int target) {
  for (;;) {
    unsigned int v = ld_flag_sc0(fp);
    if (__ballot(v < target) == 0) break;
    __builtin_amdgcn_s_sleep(1);
  }
  __asm__ __volatile__("" ::: "memory");
}

// ---------------- fused prep kernel (grid 322 x 256) ----------------
__global__ __launch_bounds__(256) void prep_all(
    const float* __restrict__ dx, const float* __restrict__ h0,
    const float* __restrict__ W1, const float* __restrict__ Whh,
    const float* __restrict__ b1, const float* __restrict__ bhh,
    const float* __restrict__ Wih, const float* __restrict__ W4,
    const float* __restrict__ b4, const float* __restrict__ bih,
    const float* __restrict__ W2, const float* __restrict__ b2,
    _Float16* __restrict__ hgh,
    _Float16* __restrict__ Wzh, float* __restrict__ bz,
    float* __restrict__ bc, _Float16* __restrict__ WcT,
    _Float16* __restrict__ w2h, unsigned int* __restrict__ bar)
{
  __shared__ __align__(16) char smem[58368];
  const int bid = blockIdx.x;
  const int tid = threadIdx.x;
  const int lane = tid & 63, wv = tid >> 6;

  if (bid == 0) {                       // zero flag region (8192 u32)
    for (int i = tid; i < 8192; i += 256) bar[i] = 0u;
  } else if (bid == 1) {                // bz
    for (int n = tid; n < 2048; n += 256)
      bz[n] = (n < 512) ? b1[n] : bhh[n - 512];
  } else if (bid < 18) {                // bc: 16 blocks x 96 rows, wave/row
    const int o0 = (bid - 2) * 96 + wv * 24;
    for (int it = 0; it < 24; ++it) {
      const int row = o0 + it;
      const float* r = Wih + row * 512 + lane * 8;
      float s = 0.f;
#pragma unroll
      for (int u = 0; u < 8; ++u) s += r[u] * b4[lane * 8 + u];
#pragma unroll
      for (int off = 32; off >= 1; off >>= 1) s += __shfl_xor(s, off);
      if (lane == 0) bc[row] = bih[row] + s;
    }
  } else if (bid < 34) {                // hgh init (f16 copy of h0)
    const int i0 = (bid - 18) * 4096 + tid * 16;
#pragma unroll
    for (int u = 0; u < 4; ++u) {
      float4 v = *(const float4*)(h0 + i0 + u * 4);
      H4 p; p.h[0] = (_Float16)v.x; p.h[1] = (_Float16)v.y;
      p.h[2] = (_Float16)v.z; p.h[3] = (_Float16)v.w;
      *(unsigned long long*)(hgh + i0 + u * 4) = p.u;
    }
  } else if (bid < 98) {                // Wzh = f16([W1;Whh]) flat copy
    const int i0 = (bid - 34) * 16384 + tid * 64;
#pragma unroll 4
    for (int u = 0; u < 16; ++u) {
      const int i = i0 + u * 4;
      const float* src = (i < 262144) ? (W1 + i) : (Whh + i - 262144);
      float4 v = *(const float4*)src;
      H4 p; p.h[0] = (_Float16)v.x; p.h[1] = (_Float16)v.y;
      p.h[2] = (_Float16)v.z; p.h[3] = (_Float16)v.w;
      *(unsigned long long*)(Wzh + i) = p.u;
    }
  } else if (bid < 194) {               // WcT[k][o] = (Wih@W4)[o][k]
    float* wih = (float*)smem;                 // 16*66
    float* w4s = (float*)(smem + 4224);        // 64*132
    const int o0 = (bid - 98) * 16;
    const int k = tid;
    float acc[16];
#pragma unroll
    for (int i = 0; i < 16; ++i) acc[i] = 0.f;
    for (int jc = 0; jc < 512; jc += 64) {
      __syncthreads();
      for (int idx = tid; idx < 16 * 64; idx += 256) {
        int oo = idx >> 6, jj = idx & 63;
        wih[oo * 66 + jj] = Wih[(o0 + oo) * 512 + jc + jj];
      }
      for (int idx = tid; idx < 64 * 131; idx += 256) {
        int r = idx / 131, c = idx - r * 131;
        w4s[r * 132 + c] = W4[(jc + r) * 131 + c];
      }
      __syncthreads();
      if (k < 131) {
        for (int jj = 0; jj < 64; ++jj) {
          float w4v = w4s[jj * 132 + k];
#pragma unroll
          for (int oo = 0; oo < 16; ++oo) acc[oo] += wih[oo * 66 + jj] * w4v;
        }
      }
    }
    if (k < 131) {
#pragma unroll
      for (int oo = 0; oo < 16; ++oo)
        WcT[k * 1536 + o0 + oo] = (_Float16)acc[oo];
    }
  } else {                              // w2h: 128 blocks, one batch row each
    float* dxa = (float*)smem;                 // 48*128 f32
    _Float16* w2t = (_Float16*)(smem + 24576); // 128*132 f16
    const int b = bid - 194;
    for (int idx = tid; idx < 48 * 128; idx += 256)
      dxa[idx] = dx[b * 6144 + idx];
    for (int hc = 0; hc < 4; ++hc) {
      __syncthreads();
      for (int idx = tid; idx < 128 * 128; idx += 256) {
        int hl = idx >> 7, i = idx & 127;
        w2t[i * 132 + hl] = (_Float16)W2[(hc * 128 + hl) * 128 + i];
      }
      __syncthreads();
      const int hh = tid & 127;
      const int tq = tid >> 7;
      const float b2v = b2[hc * 128 + hh];
      for (int tt = tq * 24; tt < tq * 24 + 24; ++tt) {
        float acc = b2v;
#pragma unroll 4
        for (int i = 0; i < 128; ++i)
          acc += dxa[tt * 128 + i] * (float)w2t[i * 132 + hh];
        w2h[(b * 48 + tt) * 512 + hc * 128 + hh] = (_Float16)acc;
      }
    }
  }
}

// ---------------- DW precompute (grid 384 x 256, after prep_all) -----------
__global__ __launch_bounds__(256) void prep_dw(
    const float* __restrict__ dx, const _Float16* __restrict__ WcT,
    unsigned int* __restrict__ DW12)
{
  __shared__ float dxu[16 * 128];
  const int j = blockIdx.x;          // 0..383
  const int tid = threadIdx.x;
  const int u0 = j * 16;             // 16 consecutive units
  const float4* src = (const float4*)(dx + (size_t)u0 * 128);
  float4* dst4 = (float4*)dxu;
  for (int i = tid; i < 512; i += 256) dst4[i] = src[i];
  __syncthreads();
  const int c0 = tid * 2;
  float acc[16][6];
#pragma unroll
  for (int u = 0; u < 16; ++u)
#pragma unroll
    for (int g = 0; g < 6; ++g) acc[u][g] = 0.f;
  for (int k = 0; k < 128; ++k) {
    const _Float16* wr = WcT + k * 1536 + c0;
    h2v w0 = *(const h2v*)(wr);
    h2v w1v = *(const h2v*)(wr + 512);
    h2v w2v = *(const h2v*)(wr + 1024);
    const float f0 = (float)w0[0],  f1 = (float)w0[1];
    const float f2 = (float)w1v[0], f3 = (float)w1v[1];
    const float f4 = (float)w2v[0], f5 = (float)w2v[1];
#pragma unroll
    for (int u = 0; u < 16; ++u) {
      const float d = dxu[u * 128 + k];
      acc[u][0] += d * f0; acc[u][1] += d * f1; acc[u][2] += d * f2;
      acc[u][3] += d * f3; acc[u][4] += d * f4; acc[u][5] += d * f5;
    }
  }
#pragma unroll
  for (int u = 0; u < 16; ++u) {
    unsigned int* o = DW12 + (size_t)(u0 + u) * 768 + tid * 3;
    HU p;
    p.h[0] = (_Float16)acc[u][0]; p.h[1] = (_Float16)acc[u][1]; o[0] = p.u;
    p.h[0] = (_Float16)acc[u][2]; p.h[1] = (_Float16)acc[u][3]; o[1] = p.u;
    p.h[0] = (_Float16)acc[u][4]; p.h[1] = (_Float16)acc[u][5]; o[2] = p.u;
  }
}

// One DW pipeline stage: consume bank CUR (4 t's), reload it 3 banks ahead.
#define DW_STEP(TB, CUR)                                                     \
  do {                                                                       \
    _Pragma("unroll")                                                        \
    for (int j = 0; j < 4; ++j) {                                            \
      const float a = asx[(TB) * 4 + j];                                     \
      HU p0, p1, p2; p0.u = CUR[j].x; p1.u = CUR[j].y; p2.u = CUR[j].z;      \
      aR0 += a * (float)p0.h[0]; aR1 += a * (float)p0.h[1];                  \
      aZ0 += a * (float)p1.h[0]; aZ1 += a * (float)p1.h[1];                  \
      aN0 += a * (float)p2.h[0]; aN1 += a * (float)p2.h[1];                  \
    }                                                                        \
    if ((TB) < 9) {                                                          \
      _Pragma("unroll")                                                      \
      for (int j = 0; j < 4; ++j)                                            \
        CUR[j] = *(const u32x3*)(dwp + (size_t)(((TB) + 3) * 4 + j) * 768);  \
    }                                                                        \
  } while (0)

// ---------------- main persistent scan kernel ----------------
__global__ __launch_bounds__(256, 1) void decoder_main(
    const float* __restrict__ xin, const float* __restrict__ h0,
    const float* __restrict__ W3, const float* __restrict__ b3,
    const float* __restrict__ Wfc, const float* __restrict__ bfc,
    const _Float16* __restrict__ Wzh, const float* __restrict__ bz,
    const _Float16* __restrict__ WcT, const float* __restrict__ bc,
    const _Float16* __restrict__ w2h, const unsigned int* __restrict__ DW12,
    _Float16* __restrict__ hgh, float* __restrict__ zg,
    unsigned int* __restrict__ bar, float* __restrict__ out)
{
  const int tid  = threadIdx.x;
  const int lane = tid & 63;
  const int wv   = tid >> 6;
  const int bid  = blockIdx.x;
  const int grp  = bid & 7;      // group id; round-robin => one XCD per group
  const int mem  = bid >> 3;     // 0..15
  const int b0   = grp * 16;
  const int myrow = b0 + mem;
  const int cb   = mem * 128;
  const int myIdx = grp * 16 + mem;
  const int base16 = grp * 16;
  unsigned int* zflag = bar;           // [block]*32 (+16..18: probe/votes)
  unsigned int* hflag = bar + 4096;    // [row]*32

  __shared__ __align__(16) _Float16 w2lds[48 * 512];     // 48 KiB
  __shared__ __align__(16) char hlds[16384];             // 16 KiB, swizzled h
  __shared__ __align__(16) unsigned int dwlds[24 * 768]; // 72 KiB: DW t=0..23
  __shared__ float xlds[48 * 4];
  __shared__ float wfcs[512];
  __shared__ float es[48];
  __shared__ float asx[48];
  __shared__ float red[4];
  __shared__ unsigned int probe_sh;

  const int m = lane & 15, q = lane >> 4;

  // ================= co-residency probe (before heavy preloads) ===========
  // 2 rounds through the sc0 path; bounded spins; agent-scope votes.
  bool fast;
  {
    if (wv == 0) {
      bool okr[2];
#pragma unroll
      for (int r = 1; r <= 2; ++r) {
        if (lane == 0)
          st_u32_sc0(zflag + (size_t)myIdx * 32 + 16, (unsigned int)r);
        const unsigned int* pp = zflag + (size_t)(base16 + (lane & 15)) * 32 + 16;
        bool ok = false;
        for (int it = 0; it < 1000 && !ok; ++it) {
          unsigned int v = ld_flag_sc0(pp);
          if (__ballot(v < (unsigned int)r) == 0) ok = true;
          else __builtin_amdgcn_s_sleep(8);
        }
        // vote (agent scope, reliable), separate slot per round
        if (lane == 0)
          st_u32(zflag + (size_t)myIdx * 32 + 16 + r, ok ? 2u : 1u);
        unsigned int* vp = zflag + (size_t)(base16 + (lane & 15)) * 32 + 16 + r;
        unsigned int v;
        for (;;) {
          v = __hip_atomic_load(vp, __ATOMIC_RELAXED, __HIP_MEMORY_SCOPE_AGENT);
          if (__ballot(v == 0u) == 0) break;
          __builtin_amdgcn_s_sleep(1);
        }
        okr[r - 1] = (__ballot(v == 2u) == ~0ull);
      }
      if (lane == 0) probe_sh = (okr[0] && okr[1]) ? 1u : 0u;
    }
    __syncthreads();
    fast = (probe_sh != 0u);
  }

  // ---- ph1 persistent weights: 2 col-tiles of 16 per wave ----
  half8 wzf[2][16];
  int   ncol[2];
  float bzv[2];
#pragma unroll
  for (int t = 0; t < 2; ++t) {
    ncol[t] = cb + (wv * 2 + t) * 16 + m;
    const _Float16* wrow = Wzh + ncol[t] * 512 + q * 8;
#pragma unroll
    for (int ks = 0; ks < 16; ++ks)
      wzf[t][ks] = *(const half8*)(wrow + ks * 32);
    bzv[t] = bz[ncol[t]];
  }
  float w3r[8];
#pragma unroll
  for (int u = 0; u < 8; ++u) w3r[u] = W3[lane * 8 + u];
  const float b3v  = b3[0];
  const float bfcv = bfc[0];

  // ---- ph3 per-thread state: owns h-cols (c0, c0+1) of row myrow ----
  const int c0 = tid * 2;
  const float bcR0 = bc[c0],        bcR1 = bc[c0 + 1];
  const float bcZ0 = bc[512 + c0],  bcZ1 = bc[513 + c0];
  const float bcN0 = bc[1024 + c0], bcN1 = bc[1025 + c0];
  float wxR[3][2], wxZ[3][2], wxN[3][2];
#pragma unroll
  for (int j2 = 0; j2 < 3; ++j2) {
    const _Float16* wr = WcT + (128 + j2) * 1536 + c0;
    wxR[j2][0] = (float)wr[0];    wxR[j2][1] = (float)wr[1];
    wxZ[j2][0] = (float)wr[512];  wxZ[j2][1] = (float)wr[513];
    wxN[j2][0] = (float)wr[1024]; wxN[j2][1] = (float)wr[1025];
  }
  float hA = h0[myrow * 512 + c0];
  float hB = h0[myrow * 512 + c0 + 1];

  const float* __restrict__ zrow = zg + (size_t)myrow * 2048;
  const unsigned int* __restrict__ dwp =
      DW12 + (size_t)myrow * 48 * 768 + (size_t)tid * 3;

  // ---- one-time LDS preload (w2h row, Wfc, xin, DW t=0..23) ----
  {
    const half8* w2src = (const half8*)(w2h + (size_t)myrow * 48 * 512);
    half8* w2dst = (half8*)w2lds;
    for (int i = tid; i < 3072; i += 256) w2dst[i] = w2src[i];
    for (int i = tid; i < 512; i += 256) wfcs[i] = Wfc[i];
    for (int i = tid; i < 144; i += 256) {
      const int t = i / 3, j2 = i - t * 3;
      xlds[t * 4 + j2] = xin[myrow * 144 + i];
    }
    const unsigned int* dwsrc = DW12 + (size_t)myrow * 48 * 768;
    for (int i = tid; i < 24 * 256; i += 256) {
      u32x3 v = *(const u32x3*)(dwsrc + (size_t)i * 3);
      *(u32x3*)(dwlds + (size_t)i * 3) = v;
    }
  }
  __syncthreads();

  for (int step = 0; step < 48; ++step) {
    // ---- stage h: per-wave poll + batched loads -> swizzled hlds ----
    {
      if (fast) {
        poll_ge_sc0(hflag + (size_t)(b0 + wv * 4 + (lane & 3)) * 32,
                    (unsigned int)step);
        f32x4 hv4[4];
        const char* ab = (const char*)hgh + (size_t)b0 * 1024 +
                         (size_t)wv * 4096 + (size_t)lane * 16;
        asm volatile(
          "global_load_dwordx4 %0, %4, off sc0\n\t"
          "global_load_dwordx4 %1, %4, off offset:1024 sc0\n\t"
          "global_load_dwordx4 %2, %4, off offset:2048 sc0\n\t"
          "global_load_dwordx4 %3, %4, off offset:3072 sc0\n\t"
          "s_waitcnt vmcnt(0)"
          : "=v"(hv4[0]), "=v"(hv4[1]), "=v"(hv4[2]), "=v"(hv4[3])
          : "v"(ab) : "memory");
#pragma unroll
        for (int v2 = 0; v2 < 4; ++v2) {
          const int c = v2 * 64 + lane;          // 16B chunk id within wave seg
          const int n0 = wv * 512 + c * 2;       // 8B unit id
          const int row = n0 >> 7;
          const int x = (n0 & 127) * 8;          // multiple of 16
          *(f32x4*)(hlds + row * 1024 + (x ^ ((row & 7) << 4))) = hv4[v2];
        }
      } else {
        poll_ge(hflag + (size_t)(b0 + wv * 4 + (lane & 3)) * 32, lane < 4,
                (unsigned int)step);
        unsigned long long hv[8];
        const char* hbase = (const char*)hgh + (size_t)b0 * 1024 + (size_t)wv * 4096;
#pragma unroll
        for (int u = 0; u < 8; ++u)
          hv[u] = ld_u64(hbase + (size_t)(u * 64 + lane) * 8);
#pragma unroll
        for (int u = 0; u < 8; ++u) {
          const int n = wv * 512 + u * 64 + lane;
          const int row = n >> 7, b8 = (n & 127) * 8;
          *(unsigned long long*)(hlds + row * 1024 + (b8 ^ ((row & 7) << 4))) = hv[u];
        }
      }
    }
    __syncthreads();

    // ---- ph1: z[16,2048] = h @ [W1|W_hh]^T + bz (MFMA, weights in regs) ----
    {
      half8 af[16];
      const char* hb = hlds + m * 1024;
      const int sw = (m & 7) << 4;
#pragma unroll
      for (int ks = 0; ks < 16; ++ks)
        af[ks] = *(const half8*)(hb + ((ks * 64 + q * 16) ^ sw));
#pragma unroll
      for (int t = 0; t < 2; ++t) {
        f32x4 acc = {bzv[t], bzv[t], bzv[t], bzv[t]};
#pragma unroll
        for (int ks = 0; ks < 16; ++ks)
          acc = __builtin_amdgcn_mfma_f32_16x16x32_f16(af[ks], wzf[t][ks], acc, 0, 0, 0);
        if (fast) {
#pragma unroll
          for (int r = 0; r < 4; ++r)
            st_f32_sc0(&zg[(size_t)(b0 + q * 4 + r) * 2048 + ncol[t]], acc[r]);
        } else {
#pragma unroll
          for (int r = 0; r < 4; ++r)
            st_f32(&zg[(size_t)(b0 + q * 4 + r) * 2048 + ncol[t]], acc[r]);
        }
      }
    }
    if (fast) drain_vm();                  // asm stores are untracked: drain
    __syncthreads();                       // (slow path: drains tracked stores)
    if (tid == 0) {
      if (fast) st_u32_sc0(&zflag[(size_t)myIdx * 32], (unsigned int)(step + 1));
      else      st_u32(&zflag[(size_t)myIdx * 32], (unsigned int)(step + 1));
    }

    // ---- combined poll: ALL 16 producers of this group ----
    if (fast)
      poll_ge_sc0(zflag + (size_t)(base16 + (lane & 15)) * 32,
                  (unsigned int)(step + 1));
    else
      poll_ge(zflag + (size_t)(base16 + (lane & 15)) * 32, lane < 16,
              (unsigned int)(step + 1));

    // ---- w1 (needed first, waited); gh issued early (wait in ph3);
    //      DW global banks prefetched (plain cached loads) ----
    float w1r[8];
    U2 tr, tz, tn2;
    if (fast) {
      f32x4 za, zb;
      const float* wp = zrow + lane * 8;
      asm volatile(
        "global_load_dwordx4 %0, %2, off sc0\n\t"
        "global_load_dwordx4 %1, %2, off offset:16 sc0\n\t"
        "s_waitcnt vmcnt(0)"
        : "=v"(za), "=v"(zb) : "v"(wp) : "memory");
      __builtin_amdgcn_sched_barrier(0);
      w1r[0] = za[0]; w1r[1] = za[1]; w1r[2] = za[2]; w1r[3] = za[3];
      w1r[4] = zb[0]; w1r[5] = zb[1]; w1r[6] = zb[2]; w1r[7] = zb[3];
      asm volatile(
        "global_load_dwordx2 %0, %3, off sc0\n\t"
        "global_load_dwordx2 %1, %4, off sc0\n\t"
        "global_load_dwordx2 %2, %5, off sc0"
        : "=v"(tr.u), "=v"(tz.u), "=v"(tn2.u)
        : "v"(zrow + 512 + c0), "v"(zrow + 1024 + c0), "v"(zrow + 1536 + c0)
        : "memory");
    } else {
#pragma unroll
      for (int u2 = 0; u2 < 4; ++u2) {
        U2 t2; t2.u = ld_u64(zrow + lane * 8 + u2 * 2);
        w1r[u2 * 2] = t2.f[0]; w1r[u2 * 2 + 1] = t2.f[1];
      }
      tr.u  = ld_u64(zrow + 512 + c0);
      tz.u  = ld_u64(zrow + 1024 + c0);
      tn2.u = ld_u64(zrow + 1536 + c0);
    }
    u32x3 bA[4], bB[4], bC[4];
#pragma unroll
    for (int j = 0; j < 4; ++j) bA[j] = *(const u32x3*)(dwp + (size_t)(24 + j) * 768);
#pragma unroll
    for (int j = 0; j < 4; ++j) bB[j] = *(const u32x3*)(dwp + (size_t)(28 + j) * 768);
#pragma unroll
    for (int j = 0; j < 4; ++j) bC[j] = *(const u32x3*)(dwp + (size_t)(32 + j) * 768);

    // ---- ph2: e -> softmax (own row, block-local) ----
    {
      for (int tt = 0; tt < 12; ++tt) {
        const int t = wv * 12 + tt;
        half8 w2v = *(const half8*)(w2lds + t * 512 + lane * 8);
        float p = 0.f;
#pragma unroll
        for (int u = 0; u < 8; ++u)
          p += w3r[u] * fast_tanh(w1r[u] + (float)w2v[u]);
#pragma unroll
        for (int off = 32; off >= 1; off >>= 1) p += __shfl_xor(p, off);
        if (lane == 0) es[t] = p + b3v;
      }
      __syncthreads();
      if (wv == 0) {
        float e = (lane < 48) ? es[lane] : -1e30f;
        float mx = e;
#pragma unroll
        for (int off = 32; off >= 1; off >>= 1) mx = fmaxf(mx, __shfl_xor(mx, off));
        float pe = (lane < 48) ? fexp2((e - mx) * 1.4426950408889634f) : 0.f;
        float s = pe;
#pragma unroll
        for (int off = 32; off >= 1; off >>= 1) s += __shfl_xor(s, off);
        float a = pe * frcp(s);
        if (lane < 48) {
          asx[lane] = a;
          if (step == 47) out[128 + myrow * 48 + lane] = a;   // alpha (last step)
        }
      }
      __syncthreads();
    }

    // ---- ph3: gi = sum_t a_t*DW + x-part + bc ; GRU ; h_new (row-local) ----
    {
      float aR0 = bcR0, aR1 = bcR1, aZ0 = bcZ0, aZ1 = bcZ1, aN0 = bcN0, aN1 = bcN1;
      // part 1: t = 0..23 from LDS
#pragma unroll 4
      for (int t = 0; t < 24; ++t) {
        const float a = asx[t];
        u32x3 d = *(const u32x3*)(dwlds + (size_t)(t * 256 + tid) * 3);
        HU p0, p1, p2; p0.u = d.x; p1.u = d.y; p2.u = d.z;
        aR0 += a * (float)p0.h[0]; aR1 += a * (float)p0.h[1];
        aZ0 += a * (float)p1.h[0]; aZ1 += a * (float)p1.h[1];
        aN0 += a * (float)p2.h[0]; aN1 += a * (float)p2.h[1];
      }
      // part 2: t = 24..47, 3-bank pipeline (banks prefetched during ph2)
      DW_STEP(6, bA);  DW_STEP(7, bB);  DW_STEP(8, bC);
      DW_STEP(9, bA);  DW_STEP(10, bB); DW_STEP(11, bC);

      const float x0 = xlds[step * 4], x1 = xlds[step * 4 + 1], x2 = xlds[step * 4 + 2];
      aR0 += x0 * wxR[0][0] + x1 * wxR[1][0] + x2 * wxR[2][0];
      aR1 += x0 * wxR[0][1] + x1 * wxR[1][1] + x2 * wxR[2][1];
      aZ0 += x0 * wxZ[0][0] + x1 * wxZ[1][0] + x2 * wxZ[2][0];
      aZ1 += x0 * wxZ[0][1] + x1 * wxZ[1][1] + x2 * wxZ[2][1];
      aN0 += x0 * wxN[0][0] + x1 * wxN[1][0] + x2 * wxN[2][0];
      aN1 += x0 * wxN[0][1] + x1 * wxN[1][1] + x2 * wxN[2][1];

      if (fast) drain_vm();   // gh asm loads (and DW) complete before use
      const float r0 = fast_sigmoid(aR0 + tr.f[0]), r1 = fast_sigmoid(aR1 + tr.f[1]);
      const float z0 = fast_sigmoid(aZ0 + tz.f[0]), z1 = fast_sigmoid(aZ1 + tz.f[1]);
      const float n0 = fast_tanh(aN0 + r0 * tn2.f[0]), n1 = fast_tanh(aN1 + r1 * tn2.f[1]);
      hA = (1.f - z0) * n0 + z0 * hA;
      hB = (1.f - z1) * n1 + z1 * hB;
      HU hp; hp.h[0] = (_Float16)hA; hp.h[1] = (_Float16)hB;
      if (fast) st_u32_sc0((unsigned int*)(hgh + myrow * 512 + c0), hp.u);
      else      st_u32((unsigned int*)(hgh + myrow * 512 + c0), hp.u);
    }
    if (fast) drain_vm();                  // h store acked in L2 before flag
    __syncthreads();
    if (tid == 0) {
      if (fast) st_u32_sc0(&hflag[(size_t)myrow * 32], (unsigned int)(step + 1));
      else      st_u32(&hflag[(size_t)myrow * 32], (unsigned int)(step + 1));
    }
  }

  // ---- epilogue: re[myrow] = h_f . Wfc + bfc (h in registers) ----
  {
    float p = hA * wfcs[c0] + hB * wfcs[c0 + 1];
#pragma unroll
    for (int off = 32; off >= 1; off >>= 1) p += __shfl_xor(p, off);
    if (lane == 0) red[wv] = p;
    __syncthreads();
    if (tid == 0) out[myrow] = red[0] + red[1] + red[2] + red[3] + bfcv;
  }
}

extern "C" void kernel_launch(void* const* d_in, const int* in_sizes, int n_in,
                              void* d_out, int out_size, void* d_ws, size_t ws_size,
                              hipStream_t stream) {
  (void)in_sizes; (void)n_in; (void)out_size; (void)ws_size;
  const float* dx  = (const float*)d_in[0];
  const float* xin = (const float*)d_in[1];
  const float* h0  = (const float*)d_in[2];
  const float* W1  = (const float*)d_in[3];
  const float* b1  = (const float*)d_in[4];
  const float* W2  = (const float*)d_in[5];
  const float* b2  = (const float*)d_in[6];
  const float* W3  = (const float*)d_in[7];
  const float* b3  = (const float*)d_in[8];
  const float* W4  = (const float*)d_in[9];
  const float* b4  = (const float*)d_in[10];
  const float* Wih = (const float*)d_in[11];
  const float* Whh = (const float*)d_in[12];
  const float* bih = (const float*)d_in[13];
  const float* bhh = (const float*)d_in[14];
  const float* Wfc = (const float*)d_in[15];
  const float* bfc = (const float*)d_in[16];

  char* ws = (char*)d_ws;
  unsigned int* bar = (unsigned int*)(ws + OFF_BAR);
  float*     bz  = (float*)(ws + OFF_BZ);
  float*     bc  = (float*)(ws + OFF_BC);
  _Float16*  Wzh = (_Float16*)(ws + OFF_WZ);
  _Float16*  WcT = (_Float16*)(ws + OFF_WCT);
  _Float16*  w2h = (_Float16*)(ws + OFF_W2H);
  _Float16*  hgh = (_Float16*)(ws + OFF_HGH);
  float*     zg  = (float*)(ws + OFF_ZG);
  unsigned int* DW12 = (unsigned int*)(ws + OFF_DW);

  prep_all<<<322, 256, 0, stream>>>(dx, h0, W1, Whh, b1, bhh, Wih, W4, b4, bih,
                                    W2, b2, hgh, Wzh, bz, bc, WcT, w2h, bar);
  prep_dw<<<384, 256, 0, stream>>>(dx, WcT, DW12);
  decoder_main<<<128, 256, 0, stream>>>(xin, h0, W3, b3, Wfc, bfc,
                                        Wzh, bz, WcT, bc, w2h, DW12,
                                        hgh, zg, bar, (float*)d_out);
}

// Round 6
// 846.409 us; speedup vs baseline: 1.4034x; 1.4034x over previous
//
#include <hip/hip_runtime.h>

// B=128, T=48, I=128, H=512. Sequential 48-step attention+GRU scan.
// R11: R9 dataflow (proven 538us) widened to 8 waves/block (512 thr, 2/SIMD)
//  - Same flags / same order / same agent-scope exchange / identical math.
//  - ph1: one 16-col tile per wave; ph2: 6 t's per wave; ph3: waves 0-3.
//  - Polls by wave 0 only + __syncthreads broadcast (R10 lesson: don't
//    multiply flag-spin traffic by wave count).
//  - 2 waves/SIMD hides dependent-chain latency in the inter-hop segments.

typedef _Float16 half8 __attribute__((ext_vector_type(8)));
typedef _Float16 h2v  __attribute__((ext_vector_type(2)));
typedef float    f32x4 __attribute__((ext_vector_type(4)));
typedef unsigned int u32x3 __attribute__((ext_vector_type(3)));

// ---------------- ws layout (bytes) ----------------
#define OFF_BAR   0u          // flags: zflag[128]*128B @0, hflag[128]*128B @16K
#define OFF_BZ    32768u      // 2048 f32 : [b1 ; b_hh]
#define OFF_BC    40960u      // 1536 f32 : W_ih@b4 + b_ih
#define OFF_WZ    65536u      // 2048*512 f16 : [W1 ; W_hh] row-major
#define OFF_WCT   2162688u    // 131*1536 f16 : (W_ih@W4)^T, k-major
#define OFF_W2H   3178496u    // 128*48*512 f16 : dx@W2^T + b2
#define OFF_HGH   9732096u    // 128*512 f16 : h (cross-block exchange)
#define OFF_ZG    9863168u    // 128*2048 f32 : z = [w1 | gh]
#define OFF_DW    10911744u   // 6144*256*3 u32 : dx@Wc^T packed 12B/(t,pair)

__device__ __forceinline__ float fexp2(float x) { return __builtin_amdgcn_exp2f(x); }
__device__ __forceinline__ float frcp(float x)  { return __builtin_amdgcn_rcpf(x); }
__device__ __forceinline__ float fast_tanh(float x) {
  x = fminf(fmaxf(x, -15.f), 15.f);
  float e = fexp2(x * 2.8853900817779268f);   // exp(2x)
  return (e - 1.f) * frcp(e + 1.f);
}
__device__ __forceinline__ float fast_sigmoid(float x) {
  x = fminf(fmaxf(x, -30.f), 30.f);
  float e = fexp2(x * 1.4426950408889634f);   // exp(x)
  return e * frcp(e + 1.f);
}

// ---- coherent (agent-scope, per-access) data movement ----
__device__ __forceinline__ void st_f32(float* p, float v) {
  __hip_atomic_store(p, v, __ATOMIC_RELAXED, __HIP_MEMORY_SCOPE_AGENT);
}
__device__ __forceinline__ unsigned long long ld_u64(const void* p) {
  return __hip_atomic_load((const unsigned long long*)p, __ATOMIC_RELAXED,
                           __HIP_MEMORY_SCOPE_AGENT);
}
__device__ __forceinline__ void st_u32(unsigned int* p, unsigned int v) {
  __hip_atomic_store(p, v, __ATOMIC_RELAXED, __HIP_MEMORY_SCOPE_AGENT);
}
union U2 { unsigned long long u; float f[2]; };
union H4 { unsigned long long u; _Float16 h[4]; };
union HU { unsigned int u; h2v h; };

// Wait until *fp >= target on all active lanes (inactive lanes auto-pass).
__device__ __forceinline__ void poll_ge(unsigned int* fp, bool active,
                                        unsigned int target) {
  for (;;) {
    unsigned int v = active
      ? __hip_atomic_load(fp, __ATOMIC_RELAXED, __HIP_MEMORY_SCOPE_AGENT)
      : target;
    if (__ballot(v < target) == 0) break;
    __builtin_amdgcn_s_sleep(1);
  }
  __asm__ __volatile__("" ::: "memory");
}

// ---------------- fused prep kernel (grid 322 x 256) ----------------
__global__ __launch_bounds__(256) void prep_all(
    const float* __restrict__ dx, const float* __restrict__ h0,
    const float* __restrict__ W1, const float* __restrict__ Whh,
    const float* __restrict__ b1, const float* __restrict__ bhh,
    const float* __restrict__ Wih, const float* __restrict__ W4,
    const float* __restrict__ b4, const float* __restrict__ bih,
    const float* __restrict__ W2, const float* __restrict__ b2,
    _Float16* __restrict__ hgh,
    _Float16* __restrict__ Wzh, float* __restrict__ bz,
    float* __restrict__ bc, _Float16* __restrict__ WcT,
    _Float16* __restrict__ w2h, unsigned int* __restrict__ bar)
{
  __shared__ __align__(16) char smem[58368];
  const int bid = blockIdx.x;
  const int tid = threadIdx.x;
  const int lane = tid & 63, wv = tid >> 6;

  if (bid == 0) {                       // zero flag region (8192 u32)
    for (int i = tid; i < 8192; i += 256) bar[i] = 0u;
  } else if (bid == 1) {                // bz
    for (int n = tid; n < 2048; n += 256)
      bz[n] = (n < 512) ? b1[n] : bhh[n - 512];
  } else if (bid < 18) {                // bc: 16 blocks x 96 rows, wave/row
    const int o0 = (bid - 2) * 96 + wv * 24;
    for (int it = 0; it < 24; ++it) {
      const int row = o0 + it;
      const float* r = Wih + row * 512 + lane * 8;
      float s = 0.f;
#pragma unroll
      for (int u = 0; u < 8; ++u) s += r[u] * b4[lane * 8 + u];
#pragma unroll
      for (int off = 32; off >= 1; off >>= 1) s += __shfl_xor(s, off);
      if (lane == 0) bc[row] = bih[row] + s;
    }
  } else if (bid < 34) {                // hgh init (f16 copy of h0)
    const int i0 = (bid - 18) * 4096 + tid * 16;
#pragma unroll
    for (int u = 0; u < 4; ++u) {
      float4 v = *(const float4*)(h0 + i0 + u * 4);
      H4 p; p.h[0] = (_Float16)v.x; p.h[1] = (_Float16)v.y;
      p.h[2] = (_Float16)v.z; p.h[3] = (_Float16)v.w;
      *(unsigned long long*)(hgh + i0 + u * 4) = p.u;
    }
  } else if (bid < 98) {                // Wzh = f16([W1;Whh]) flat copy
    const int i0 = (bid - 34) * 16384 + tid * 64;
#pragma unroll 4
    for (int u = 0; u < 16; ++u) {
      const int i = i0 + u * 4;
      const float* src = (i < 262144) ? (W1 + i) : (Whh + i - 262144);
      float4 v = *(const float4*)src;
      H4 p; p.h[0] = (_Float16)v.x; p.h[1] = (_Float16)v.y;
      p.h[2] = (_Float16)v.z; p.h[3] = (_Float16)v.w;
      *(unsigned long long*)(Wzh + i) = p.u;
    }
  } else if (bid < 194) {               // WcT[k][o] = (Wih@W4)[o][k]
    float* wih = (float*)smem;                 // 16*66
    float* w4s = (float*)(smem + 4224);        // 64*132
    const int o0 = (bid - 98) * 16;
    const int k = tid;
    float acc[16];
#pragma unroll
    for (int i = 0; i < 16; ++i) acc[i] = 0.f;
    for (int jc = 0; jc < 512; jc += 64) {
      __syncthreads();
      for (int idx = tid; idx < 16 * 64; idx += 256) {
        int oo = idx >> 6, jj = idx & 63;
        wih[oo * 66 + jj] = Wih[(o0 + oo) * 512 + jc + jj];
      }
      for (int idx = tid; idx < 64 * 131; idx += 256) {
        int r = idx / 131, c = idx - r * 131;
        w4s[r * 132 + c] = W4[(jc + r) * 131 + c];
      }
      __syncthreads();
      if (k < 131) {
        for (int jj = 0; jj < 64; ++jj) {
          float w4v = w4s[jj * 132 + k];
#pragma unroll
          for (int oo = 0; oo < 16; ++oo) acc[oo] += wih[oo * 66 + jj] * w4v;
        }
      }
    }
    if (k < 131) {
#pragma unroll
      for (int oo = 0; oo < 16; ++oo)
        WcT[k * 1536 + o0 + oo] = (_Float16)acc[oo];
    }
  } else {                              // w2h: 128 blocks, one batch row each
    float* dxa = (float*)smem;                 // 48*128 f32
    _Float16* w2t = (_Float16*)(smem + 24576); // 128*132 f16
    const int b = bid - 194;
    for (int idx = tid; idx < 48 * 128; idx += 256)
      dxa[idx] = dx[b * 6144 + idx];
    for (int hc = 0; hc < 4; ++hc) {
      __syncthreads();
      for (int idx = tid; idx < 128 * 128; idx += 256) {
        int hl = idx >> 7, i = idx & 127;
        w2t[i * 132 + hl] = (_Float16)W2[(hc * 128 + hl) * 128 + i];
      }
      __syncthreads();
      const int hh = tid & 127;
      const int tq = tid >> 7;
      const float b2v = b2[hc * 128 + hh];
      for (int tt = tq * 24; tt < tq * 24 + 24; ++tt) {
        float acc = b2v;
#pragma unroll 4
        for (int i = 0; i < 128; ++i)
          acc += dxa[tt * 128 + i] * (float)w2t[i * 132 + hh];
        w2h[(b * 48 + tt) * 512 + hc * 128 + hh] = (_Float16)acc;
      }
    }
  }
}

// ---------------- DW precompute (grid 384 x 256, after prep_all) -----------
// Packed layout: DW12[unit][pair][3 u32], pair = h-col pair, 12B contiguous.
__global__ __launch_bounds__(256) void prep_dw(
    const float* __restrict__ dx, const _Float16* __restrict__ WcT,
    unsigned int* __restrict__ DW12)
{
  __shared__ float dxu[16 * 128];
  const int j = blockIdx.x;          // 0..383
  const int tid = threadIdx.x;
  const int u0 = j * 16;             // 16 consecutive units
  const float4* src = (const float4*)(dx + (size_t)u0 * 128);
  float4* dst4 = (float4*)dxu;
  for (int i = tid; i < 512; i += 256) dst4[i] = src[i];
  __syncthreads();
  const int c0 = tid * 2;
  float acc[16][6];
#pragma unroll
  for (int u = 0; u < 16; ++u)
#pragma unroll
    for (int g = 0; g < 6; ++g) acc[u][g] = 0.f;
  for (int k = 0; k < 128; ++k) {
    const _Float16* wr = WcT + k * 1536 + c0;
    h2v w0 = *(const h2v*)(wr);
    h2v w1v = *(const h2v*)(wr + 512);
    h2v w2v = *(const h2v*)(wr + 1024);
    const float f0 = (float)w0[0],  f1 = (float)w0[1];
    const float f2 = (float)w1v[0], f3 = (float)w1v[1];
    const float f4 = (float)w2v[0], f5 = (float)w2v[1];
#pragma unroll
    for (int u = 0; u < 16; ++u) {
      const float d = dxu[u * 128 + k];
      acc[u][0] += d * f0; acc[u][1] += d * f1; acc[u][2] += d * f2;
      acc[u][3] += d * f3; acc[u][4] += d * f4; acc[u][5] += d * f5;
    }
  }
#pragma unroll
  for (int u = 0; u < 16; ++u) {
    unsigned int* o = DW12 + (size_t)(u0 + u) * 768 + tid * 3;
    HU p;
    p.h[0] = (_Float16)acc[u][0]; p.h[1] = (_Float16)acc[u][1]; o[0] = p.u;
    p.h[0] = (_Float16)acc[u][2]; p.h[1] = (_Float16)acc[u][3]; o[1] = p.u;
    p.h[0] = (_Float16)acc[u][4]; p.h[1] = (_Float16)acc[u][5]; o[2] = p.u;
  }
}

// One DW pipeline stage: consume bank CUR (4 t's), reload it 3 banks ahead.
#define DW_STEP(TB, CUR)                                                     \
  do {                                                                       \
    _Pragma("unroll")                                                        \
    for (int j = 0; j < 4; ++j) {                                            \
      const float a = asx[(TB) * 4 + j];                                     \
      HU p0, p1, p2; p0.u = CUR[j].x; p1.u = CUR[j].y; p2.u = CUR[j].z;      \
      aR0 += a * (float)p0.h[0]; aR1 += a * (float)p0.h[1];                  \
      aZ0 += a * (float)p1.h[0]; aZ1 += a * (float)p1.h[1];                  \
      aN0 += a * (float)p2.h[0]; aN1 += a * (float)p2.h[1];                  \
    }                                                                        \
    if ((TB) < 9) {                                                          \
      _Pragma("unroll")                                                      \
      for (int j = 0; j < 4; ++j)                                            \
        CUR[j] = *(const u32x3*)(dwp + (size_t)(((TB) + 3) * 4 + j) * 768);  \
    }                                                                        \
  } while (0)

// ---------------- main persistent scan kernel (512 threads, 8 waves) -------
__global__ __launch_bounds__(512, 2) void decoder_main(
    const float* __restrict__ xin, const float* __restrict__ h0,
    const float* __restrict__ W3, const float* __restrict__ b3,
    const float* __restrict__ Wfc, const float* __restrict__ bfc,
    const _Float16* __restrict__ Wzh, const float* __restrict__ bz,
    const _Float16* __restrict__ WcT, const float* __restrict__ bc,
    const _Float16* __restrict__ w2h, const unsigned int* __restrict__ DW12,
    _Float16* __restrict__ hgh, float* __restrict__ zg,
    unsigned int* __restrict__ bar, float* __restrict__ out)
{
  const int tid  = threadIdx.x;
  const int lane = tid & 63;
  const int wv   = tid >> 6;     // 0..7
  const int bid  = blockIdx.x;
  const int grp  = bid & 7;      // XCD-local heuristic (perf only)
  const int mem  = bid >> 3;     // 0..15
  const int b0   = grp * 16;
  const int myrow = b0 + mem;
  const int cb   = mem * 128;
  const int myIdx = grp * 16 + mem;
  const int base16 = grp * 16;
  unsigned int* zflag = bar;           // [block]*32
  unsigned int* hflag = bar + 4096;    // [row]*32

  __shared__ __align__(16) _Float16 w2lds[48 * 512];     // 48 KiB
  __shared__ __align__(16) char hlds[16384];             // 16 KiB, swizzled h
  __shared__ __align__(16) unsigned int dwlds[24 * 768]; // 72 KiB: DW t=0..23
  __shared__ float xlds[48 * 4];
  __shared__ float wfcs[512];
  __shared__ float es[48];
  __shared__ float asx[48];
  __shared__ float red[4];

  const int m = lane & 15, q = lane >> 4;

  // ---- ph1 persistent weights: ONE 16-col tile per wave (8x16 = 128) ----
  half8 wzf[16];
  const int ncol = cb + wv * 16 + m;
  {
    const _Float16* wrow = Wzh + ncol * 512 + q * 8;
#pragma unroll
    for (int ks = 0; ks < 16; ++ks)
      wzf[ks] = *(const half8*)(wrow + ks * 32);
  }
  const float bzv = bz[ncol];
  float w3r[8];
#pragma unroll
  for (int u = 0; u < 8; ++u) w3r[u] = W3[lane * 8 + u];
  const float b3v  = b3[0];
  const float bfcv = bfc[0];

  // ---- ph3 per-thread state (meaningful for tid<256; clamped elsewhere) ----
  const int t2 = tid & 255;
  const int c0 = t2 * 2;
  const float bcR0 = bc[c0],        bcR1 = bc[c0 + 1];
  const float bcZ0 = bc[512 + c0],  bcZ1 = bc[513 + c0];
  const float bcN0 = bc[1024 + c0], bcN1 = bc[1025 + c0];
  float wxR[3][2], wxZ[3][2], wxN[3][2];
#pragma unroll
  for (int j2 = 0; j2 < 3; ++j2) {
    const _Float16* wr = WcT + (128 + j2) * 1536 + c0;
    wxR[j2][0] = (float)wr[0];    wxR[j2][1] = (float)wr[1];
    wxZ[j2][0] = (float)wr[512];  wxZ[j2][1] = (float)wr[513];
    wxN[j2][0] = (float)wr[1024]; wxN[j2][1] = (float)wr[1025];
  }
  float hA = h0[myrow * 512 + c0];
  float hB = h0[myrow * 512 + c0 + 1];

  const float* __restrict__ zrow = zg + (size_t)myrow * 2048;
  const unsigned int* __restrict__ dwp =
      DW12 + (size_t)myrow * 48 * 768 + (size_t)t2 * 3;

  // ---- one-time LDS preload (w2h row, Wfc, xin, DW t=0..23) ----
  {
    const half8* w2src = (const half8*)(w2h + (size_t)myrow * 48 * 512);
    half8* w2dst = (half8*)w2lds;
    for (int i = tid; i < 3072; i += 512) w2dst[i] = w2src[i];
    for (int i = tid; i < 512; i += 512) wfcs[i] = Wfc[i];
    for (int i = tid; i < 144; i += 512) {
      const int t = i / 3, j2 = i - t * 3;
      xlds[t * 4 + j2] = xin[myrow * 144 + i];
    }
    const unsigned int* dwsrc = DW12 + (size_t)myrow * 48 * 768;
    for (int i = tid; i < 24 * 256; i += 512) {
      u32x3 v = *(const u32x3*)(dwsrc + (size_t)i * 3);
      *(u32x3*)(dwlds + (size_t)i * 3) = v;
    }
  }
  __syncthreads();

  for (int step = 0; step < 48; ++step) {
    // ---- h-hop: wave0 polls all 16 rows, barrier, all waves load ----
    if (wv == 0)
      poll_ge(hflag + (size_t)(b0 + (lane & 15)) * 32, lane < 16,
              (unsigned int)step);
    __syncthreads();
    {
      unsigned long long hv[4];
      const char* hbase = (const char*)hgh + (size_t)b0 * 1024 + (size_t)wv * 2048;
#pragma unroll
      for (int u = 0; u < 4; ++u)
        hv[u] = ld_u64(hbase + (size_t)(u * 64 + lane) * 8);
#pragma unroll
      for (int u = 0; u < 4; ++u) {
        const int n = wv * 256 + u * 64 + lane;
        const int row = n >> 7, b8 = (n & 127) * 8;
        *(unsigned long long*)(hlds + row * 1024 + (b8 ^ ((row & 7) << 4))) = hv[u];
      }
    }
    __syncthreads();

    // ---- ph1: z[16,2048] = h @ [W1|W_hh]^T + bz (one col-tile per wave) ----
    {
      half8 af[16];
      const char* hb = hlds + m * 1024;
      const int sw = (m & 7) << 4;
#pragma unroll
      for (int ks = 0; ks < 16; ++ks)
        af[ks] = *(const half8*)(hb + ((ks * 64 + q * 16) ^ sw));
      f32x4 acc = {bzv, bzv, bzv, bzv};
#pragma unroll
      for (int ks = 0; ks < 16; ++ks)
        acc = __builtin_amdgcn_mfma_f32_16x16x32_f16(af[ks], wzf[ks], acc, 0, 0, 0);
#pragma unroll
      for (int r = 0; r < 4; ++r)
        st_f32(&zg[(size_t)(b0 + q * 4 + r) * 2048 + ncol], acc[r]);
    }
    __syncthreads();                       // drains vmcnt: z acked at MALL
    if (tid == 0) st_u32(&zflag[(size_t)myIdx * 32], (unsigned int)(step + 1));

    // ---- z-hop: wave0 polls all 16 producers, barrier ----
    if (wv == 0)
      poll_ge(zflag + (size_t)(base16 + (lane & 15)) * 32, lane < 16,
              (unsigned int)(step + 1));
    __syncthreads();

    // ---- early issue: w1 row (all waves, per-lane slice); gh + DW banks
    //      (waves 0-3). RT hides under ph2's tanh. ----
    float w1r[8];
#pragma unroll
    for (int u2 = 0; u2 < 4; ++u2) {
      U2 t2u; t2u.u = ld_u64(zrow + lane * 8 + u2 * 2);
      w1r[u2 * 2] = t2u.f[0]; w1r[u2 * 2 + 1] = t2u.f[1];
    }
    U2 tr, tz, tn2;
    u32x3 bA[4], bB[4], bC[4];
    if (tid < 256) {
      tr.u  = ld_u64(zrow + 512 + c0);
      tz.u  = ld_u64(zrow + 1024 + c0);
      tn2.u = ld_u64(zrow + 1536 + c0);
#pragma unroll
      for (int j = 0; j < 4; ++j) bA[j] = *(const u32x3*)(dwp + (size_t)(24 + j) * 768);
#pragma unroll
      for (int j = 0; j < 4; ++j) bB[j] = *(const u32x3*)(dwp + (size_t)(28 + j) * 768);
#pragma unroll
      for (int j = 0; j < 4; ++j) bC[j] = *(const u32x3*)(dwp + (size_t)(32 + j) * 768);
    }

    // ---- ph2: e -> softmax (6 t's per wave) ----
    {
      for (int tt = 0; tt < 6; ++tt) {
        const int t = wv * 6 + tt;
        half8 w2v = *(const half8*)(w2lds + t * 512 + lane * 8);
        float p = 0.f;
#pragma unroll
        for (int u = 0; u < 8; ++u)
          p += w3r[u] * fast_tanh(w1r[u] + (float)w2v[u]);
#pragma unroll
        for (int off = 32; off >= 1; off >>= 1) p += __shfl_xor(p, off);
        if (lane == 0) es[t] = p + b3v;
      }
      __syncthreads();
      if (wv == 0) {
        float e = (lane < 48) ? es[lane] : -1e30f;
        float mx = e;
#pragma unroll
        for (int off = 32; off >= 1; off >>= 1) mx = fmaxf(mx, __shfl_xor(mx, off));
        float pe = (lane < 48) ? fexp2((e - mx) * 1.4426950408889634f) : 0.f;
        float s = pe;
#pragma unroll
        for (int off = 32; off >= 1; off >>= 1) s += __shfl_xor(s, off);
        float a = pe * frcp(s);
        if (lane < 48) {
          asx[lane] = a;
          if (step == 47) out[128 + myrow * 48 + lane] = a;   // alpha (last step)
        }
      }
      __syncthreads();
    }

    // ---- ph3 (waves 0-3): gi = sum_t a_t*DW + x + bc ; GRU ; h_new ----
    if (tid < 256) {
      float aR0 = bcR0, aR1 = bcR1, aZ0 = bcZ0, aZ1 = bcZ1, aN0 = bcN0, aN1 = bcN1;
      // part 1: t = 0..23 from LDS
#pragma unroll 4
      for (int t = 0; t < 24; ++t) {
        const float a = asx[t];
        u32x3 d = *(const u32x3*)(dwlds + (size_t)(t * 256 + t2) * 3);
        HU p0, p1, p2; p0.u = d.x; p1.u = d.y; p2.u = d.z;
        aR0 += a * (float)p0.h[0]; aR1 += a * (float)p0.h[1];
        aZ0 += a * (float)p1.h[0]; aZ1 += a * (float)p1.h[1];
        aN0 += a * (float)p2.h[0]; aN1 += a * (float)p2.h[1];
      }
      // part 2: t = 24..47, 3-bank pipeline (banks prefetched during ph2)
      DW_STEP(6, bA);  DW_STEP(7, bB);  DW_STEP(8, bC);
      DW_STEP(9, bA);  DW_STEP(10, bB); DW_STEP(11, bC);

      const float x0 = xlds[step * 4], x1 = xlds[step * 4 + 1], x2 = xlds[step * 4 + 2];
      aR0 += x0 * wxR[0][0] + x1 * wxR[1][0] + x2 * wxR[2][0];
      aR1 += x0 * wxR[0][1] + x1 * wxR[1][1] + x2 * wxR[2][1];
      aZ0 += x0 * wxZ[0][0] + x1 * wxZ[1][0] + x2 * wxZ[2][0];
      aZ1 += x0 * wxZ[0][1] + x1 * wxZ[1][1] + x2 * wxZ[2][1];
      aN0 += x0 * wxN[0][0] + x1 * wxN[1][0] + x2 * wxN[2][0];
      aN1 += x0 * wxN[0][1] + x1 * wxN[1][1] + x2 * wxN[2][1];

      const float r0 = fast_sigmoid(aR0 + tr.f[0]), r1 = fast_sigmoid(aR1 + tr.f[1]);
      const float z0 = fast_sigmoid(aZ0 + tz.f[0]), z1 = fast_sigmoid(aZ1 + tz.f[1]);
      const float n0 = fast_tanh(aN0 + r0 * tn2.f[0]), n1 = fast_tanh(aN1 + r1 * tn2.f[1]);
      hA = (1.f - z0) * n0 + z0 * hA;
      hB = (1.f - z1) * n1 + z1 * hB;
      HU hp; hp.h[0] = (_Float16)hA; hp.h[1] = (_Float16)hB;
      st_u32((unsigned int*)(hgh + myrow * 512 + c0), hp.u);   // h exchange
    }
    __syncthreads();                       // drains vmcnt: h acked at MALL
    if (tid == 0) st_u32(&hflag[(size_t)myrow * 32], (unsigned int)(step + 1));
  }

  // ---- epilogue: re[myrow] = h_f . Wfc + bfc (h in registers) ----
  if (tid < 256) {
    float p = hA * wfcs[c0] + hB * wfcs[c0 + 1];
#pragma unroll
    for (int off = 32; off >= 1; off >>= 1) p += __shfl_xor(p, off);
    if (lane == 0) red[wv] = p;
  }
  __syncthreads();
  if (tid == 0) out[myrow] = red[0] + red[1] + red[2] + red[3] + bfcv;
}

extern "C" void kernel_launch(void* const* d_in, const int* in_sizes, int n_in,
                              void* d_out, int out_size, void* d_ws, size_t ws_size,
                              hipStream_t stream) {
  (void)in_sizes; (void)n_in; (void)out_size; (void)ws_size;
  const float* dx  = (const float*)d_in[0];
  const float* xin = (const float*)d_in[1];
  const float* h0  = (const float*)d_in[2];
  const float* W1  = (const float*)d_in[3];
  const float* b1  = (const float*)d_in[4];
  const float* W2  = (const float*)d_in[5];
  const float* b2  = (const float*)d_in[6];
  const float* W3  = (const float*)d_in[7];
  const float* b3  = (const float*)d_in[8];
  const float* W4  = (const float*)d_in[9];
  const float* b4  = (const float*)d_in[10];
  const float* Wih = (const float*)d_in[11];
  const float* Whh = (const float*)d_in[12];
  const float* bih = (const float*)d_in[13];
  const float* bhh = (const float*)d_in[14];
  const float* Wfc = (const float*)d_in[15];
  const float* bfc = (const float*)d_in[16];

  char* ws = (char*)d_ws;
  unsigned int* bar = (unsigned int*)(ws + OFF_BAR);
  float*     bz  = (float*)(ws + OFF_BZ);
  float*     bc  = (float*)(ws + OFF_BC);
  _Float16*  Wzh = (_Float16*)(ws + OFF_WZ);
  _Float16*  WcT = (_Float16*)(ws + OFF_WCT);
  _Float16*  w2h = (_Float16*)(ws + OFF_W2H);
  _Float16*  hgh = (_Float16*)(ws + OFF_HGH);
  float*     zg  = (float*)(ws + OFF_ZG);
  unsigned int* DW12 = (unsigned int*)(ws + OFF_DW);

  prep_all<<<322, 256, 0, stream>>>(dx, h0, W1, Whh, b1, bhh, Wih, W4, b4, bih,
                                    W2, b2, hgh, Wzh, bz, bc, WcT, w2h, bar);
  prep_dw<<<384, 256, 0, stream>>>(dx, WcT, DW12);
  decoder_main<<<128, 512, 0, stream>>>(xin, h0, W3, b3, Wfc, bfc,
                                        Wzh, bz, WcT, bc, w2h, DW12,
                                        hgh, zg, bar, (float*)d_out);
}